// Round 14
// baseline (233.461 us; speedup 1.0000x reference)
//
#include <hip/hip_runtime.h>
#include <hip/hip_bf16.h>
#include <math.h>

#define TOKENS 16384
#define DIM 4096
#define NEXP 64
#define TOPK 8
#define FILTER_R 0.62f
#define LOAD_LR 0.001f
#define EPS_GAP 1e-4f      // bf16x3 logit err ~1e-6 RMS; 100x margin

typedef __attribute__((ext_vector_type(8))) short bf16x8;
typedef __attribute__((ext_vector_type(4))) float f32x4;

#define NSTEP 128                  // total K-steps of 32
#define TPB 32                     // tokens per block
#define BK 128                     // floats per chunk per row
#define NCH (DIM / BK)             // 32 chunks
#define BFRAG_U4 (NSTEP * 4 * 64)  // 32768 uint4 = 512KB per array

// ws: Bhi[512KB] | Blo[512KB] | hist[64] | flag_cnt | done_cnt | flag_list[16384]

__device__ __forceinline__ unsigned bf16_hi_bits(unsigned u) {
    return (u + 0x7fffu + ((u >> 16) & 1u)) & 0xffff0000u;   // RTNE bf16 (as f32 bits)
}

// Coalesced pack (R10-verified mapping): thread tid=((s*4+f)*64+lane) emits the
// 8 consecutive-k elems of one B-fragment slot: n=f*16+(lane&15), k=s*32+(lane>>4)*8+e
__global__ void pack_kernel(const float* __restrict__ W,
                            uint4* __restrict__ Bhi,
                            uint4* __restrict__ Blo,
                            int* __restrict__ hist) {
    int tid = blockIdx.x * blockDim.x + threadIdx.x;     // 0 .. 32767
    if (blockIdx.x == 0 && threadIdx.x < NEXP + 2) hist[threadIdx.x] = 0;
    int s = tid >> 8, f = (tid >> 6) & 3, lane = tid & 63;
    int n = f * 16 + (lane & 15);
    int k0 = s * 32 + ((lane >> 4) << 3);
    const float* wp = W + (size_t)n * DIM + k0;
    float4 wa = *(const float4*)wp;
    float4 wb = *(const float4*)(wp + 4);
    float fe[8] = {wa.x, wa.y, wa.z, wa.w, wb.x, wb.y, wb.z, wb.w};
    unsigned hh[8], ll[8];
#pragma unroll
    for (int e = 0; e < 8; ++e) {
        unsigned u = __float_as_uint(fe[e]);
        unsigned hr = bf16_hi_bits(u);
        hh[e] = hr >> 16;
        float lo = fe[e] - __uint_as_float(hr);
        ll[e] = bf16_hi_bits(__float_as_uint(lo)) >> 16;
    }
    Bhi[tid] = make_uint4(hh[0] | (hh[1] << 16), hh[2] | (hh[3] << 16),
                          hh[4] | (hh[5] << 16), hh[6] | (hh[7] << 16));
    Blo[tid] = make_uint4(ll[0] | (ll[1] << 16), ll[2] | (ll[3] << 16),
                          ll[4] | (ll[5] << 16), ll[6] | (ll[7] << 16));
}

#define MF(A, B, C) C = __builtin_amdgcn_mfma_f32_16x16x32_bf16(A, B, C, 0, 0, 0)

#define SPLIT8(A0, A1, AH, AL) {                                      \
    float fe[8] = {A0.x,A0.y,A0.z,A0.w,A1.x,A1.y,A1.z,A1.w};          \
    short he[8], le[8];                                               \
    _Pragma("unroll")                                                 \
    for (int e_ = 0; e_ < 8; ++e_) {                                  \
        unsigned u_ = __float_as_uint(fe[e_]);                        \
        unsigned hr_ = bf16_hi_bits(u_);                              \
        he[e_] = (short)(hr_ >> 16);                                  \
        float lo_ = fe[e_] - __uint_as_float(hr_);                    \
        le[e_] = (short)(bf16_hi_bits(__float_as_uint(lo_)) >> 16); } \
    AH = (bf16x8){he[0],he[1],he[2],he[3],he[4],he[5],he[6],he[7]};   \
    AL = (bf16x8){le[0],le[1],le[2],le[3],le[4],le[5],le[6],le[7]}; }

// 512 blocks x 256 thr (4 waves = 2 M-halves x 2 F-halves); disjoint outputs,
// full K per wave. x staged COALESCED (row-contiguous gload_lds, unit-XOR
// swizzle p^=(r&7) on source, same XOR on read); W direct from L2 (coalesced).
__global__ __launch_bounds__(256, 2) void router_kernel(
    const float* __restrict__ x,
    const float* __restrict__ b,
    const float* __restrict__ bi,
    const float* __restrict__ rand_u,
    const uint4* __restrict__ Bh4,
    const uint4* __restrict__ Bl4,
    float* __restrict__ out,          // probs | indices-as-float | bi_new
    int* __restrict__ hist_g) {       // hist[64] | flag_cnt | done_cnt | flag_list
    __shared__ float xs[2][TPB][BK];       // 32KB double-buffered x tile (swizzled)
    __shared__ float part[TPB][NEXP + 1];  // 8.3KB final logits (disjoint writes)
    __shared__ int lds_hist[NEXP];

    const int lane = threadIdx.x & 63;
    const int wid  = __builtin_amdgcn_readfirstlane(threadIdx.x >> 6);  // 0..3
    const int m  = wid & 1;            // M-half: tokens 16m..16m+15
    const int fp = wid >> 1;           // F-half: f-groups {2fp, 2fp+1}
    if (threadIdx.x < NEXP) lds_hist[threadIdx.x] = 0;

    const int t0 = blockIdx.x * TPB;

    // stage chunk c into buffer bf: wave wid stages rows 8wid..8wid+7.
    // One instr = 1KB = 2 complete rows (512B each) -> fully coalesced source.
    // Source unit index pre-swizzled (p ^ (r&7)) so swizzled read is bank-clean.
    auto stage = [&](int c, int bf) {
#pragma unroll
        for (int i = 0; i < 4; ++i) {
            const int rbase = 8 * wid + 2 * i;
            const int r = rbase + (lane >> 5);          // per-lane row
            const int p = lane & 31;                    // dest float4-unit in row
            const float* g = x + (size_t)(t0 + r) * DIM + c * BK
                               + ((p ^ (r & 7)) << 2);
            __builtin_amdgcn_global_load_lds(
                (const __attribute__((address_space(1))) void*)g,
                (__attribute__((address_space(3))) void*)&xs[bf][rbase][0], 16, 0, 0);
        }
    };

    f32x4 acc0 = {0,0,0,0}, acc1 = {0,0,0,0};   // f-groups 2fp, 2fp+1
    const int arow = m * 16 + (lane & 15);      // A row (token) in tile
    const int kg = lane >> 4;                   // A k-subgroup (0..3)
    const int rx = arow & 7;                    // read-side XOR key

    stage(0, 0);
    __syncthreads();

    for (int c = 0; c < NCH; ++c) {
        const int bf = c & 1;
        if (c + 1 < NCH) stage(c + 1, bf ^ 1);

#pragma unroll
        for (int s = 0; s < 4; ++s) {           // 4 K-steps of 32 per chunk
            const int v0 = s * 8 + kg * 2;      // float4-unit of A fragment
            float4 xa = *(const float4*)&xs[bf][arow][((v0) ^ rx) << 2];
            float4 xb = *(const float4*)&xs[bf][arow][((v0 + 1) ^ rx) << 2];
            bf16x8 ah, al;
            SPLIT8(xa, xb, ah, al);
            const int S = c * 4 + s;            // global K-step
#pragma unroll
            for (int fl = 0; fl < 2; ++fl) {
                const int f = fp * 2 + fl;
                uint4 bhv = Bh4[((size_t)S * 4 + f) * 64 + lane];
                uint4 blv = Bl4[((size_t)S * 4 + f) * 64 + lane];
                bf16x8 bh_ = __builtin_bit_cast(bf16x8, bhv);
                bf16x8 bl_ = __builtin_bit_cast(bf16x8, blv);
                if (fl == 0) { MF(ah, bh_, acc0); MF(al, bh_, acc0); MF(ah, bl_, acc0); }
                else         { MF(ah, bh_, acc1); MF(al, bh_, acc1); MF(ah, bl_, acc1); }
            }
        }
        __syncthreads();
    }

    // disjoint C write: token = m*16 + kg*4 + r, expert = f*16 + (lane&15)
#pragma unroll
    for (int r = 0; r < 4; ++r) {
        const int tr = m * 16 + kg * 4 + r;
        part[tr][(fp * 2 + 0) * 16 + (lane & 15)] = acc0[r];
        part[tr][(fp * 2 + 1) * 16 + (lane & 15)] = acc1[r];
    }
    __syncthreads();

    const float b_lane  = b[lane];
    const float bi_lane = bi[lane];
    int* flag_cnt  = hist_g + NEXP;
    int* flag_list = hist_g + NEXP + 2;

    for (int t = wid * 8; t < wid * 8 + 8; ++t) {
        const float vub = part[t][lane] + b_lane;
        float cur_l = vub + bi_lane;

        float selv  = -INFINITY;
        int   selidx = 0;
#pragma unroll
        for (int j = 0; j <= TOPK; ++j) {       // top-9: gap-check 8/9 boundary too
            float bv = cur_l;
            int   bidx = lane;
#pragma unroll
            for (int s = 1; s < 64; s <<= 1) {
                float ov = __shfl_xor(bv, s, 64);
                int   oi = __shfl_xor(bidx, s, 64);
                bool take = (ov > bv) || (ov == bv && oi < bidx);
                if (take) { bv = ov; bidx = oi; }
            }
            if (lane == j) { selv = bv; selidx = bidx; }
            if (lane == bidx) cur_l = -INFINITY;
        }

        const int tt = t0 + t;
        float nxtv = __shfl_down(selv, 1, 64);
        bool  bad  = (lane < TOPK) && (selv - nxtv < EPS_GAP);
        if (__any(bad)) {
            if (lane == 0) {
                int p = atomicAdd(flag_cnt, 1);
                if (p < TOKENS) flag_list[p] = tt;
            }
        } else {
            float out_logit = __shfl(vub, selidx, 64);
            float sv = (lane < TOPK) ? out_logit : -INFINITY;
            float mx = sv;
            mx = fmaxf(mx, __shfl_xor(mx, 1, 64));
            mx = fmaxf(mx, __shfl_xor(mx, 2, 64));
            mx = fmaxf(mx, __shfl_xor(mx, 4, 64));
            float e = (lane < TOPK) ? expf(sv - mx) : 0.f;
            float ssum = e;
            ssum += __shfl_xor(ssum, 1, 64);
            ssum += __shfl_xor(ssum, 2, 64);
            ssum += __shfl_xor(ssum, 4, 64);
            if (lane < TOPK) {
                float p = e / ssum;
                float r = rand_u[tt * TOPK + lane];
                out[tt * TOPK + lane] = (r > FILTER_R) ? p : 0.f;
                out[TOKENS * TOPK + tt * TOPK + lane] = (float)selidx;
                atomicAdd(&lds_hist[selidx], 1);
            }
        }
    }

    __syncthreads();
    if (threadIdx.x < NEXP) atomicAdd(&hist_g[threadIdx.x], lds_hist[threadIdx.x]);
}

// exact f64 redo per flagged token (4-wave K-split); last block does bias update
__global__ __launch_bounds__(256) void fallback_kernel(
    const float* __restrict__ x,
    const float* __restrict__ W,
    const float* __restrict__ b,
    const float* __restrict__ bi,
    const float* __restrict__ rand_u,
    float* __restrict__ out,
    int* __restrict__ hist_g) {
    __shared__ double part[4][64];
    __shared__ int last_flag;
    const int lane = threadIdx.x & 63;
    const int wave = threadIdx.x >> 6;
    const int* flag_cnt  = hist_g + NEXP;
    int* done_cnt        = hist_g + NEXP + 1;
    const int* flag_list = hist_g + NEXP + 2;
    int n = *flag_cnt; if (n > TOKENS) n = TOKENS;

    for (int i = blockIdx.x; i < n; i += gridDim.x) {
        const int tt = flag_list[i];
        const float4* xr = (const float4*)(x + (size_t)tt * DIM);
        const float4* wr = (const float4*)(W + (size_t)lane * DIM);
        double d0 = 0.0, d1 = 0.0;
#pragma unroll 8
        for (int k4 = wave * 256; k4 < (wave + 1) * 256; ++k4) {
            float4 xv = xr[k4];
            float4 wv = wr[k4];
            d0 = fma((double)xv.x, (double)wv.x, d0);
            d1 = fma((double)xv.y, (double)wv.y, d1);
            d0 = fma((double)xv.z, (double)wv.z, d0);
            d1 = fma((double)xv.w, (double)wv.w, d1);
        }
        part[wave][lane] = d0 + d1;
        __syncthreads();
        if (wave == 0) {
            const double dvub = ((part[0][lane] + part[1][lane]) +
                                 (part[2][lane] + part[3][lane])) + (double)b[lane];
            double dcur = dvub + (double)bi[lane];
            float out_logit = -INFINITY;
            int   out_idx   = 0;
#pragma unroll
            for (int j = 0; j < TOPK; ++j) {
                double bv = dcur;
                int    bidx = lane;
#pragma unroll
                for (int s = 1; s < 64; s <<= 1) {
                    double ov = __shfl_xor(bv, s, 64);
                    int    oi = __shfl_xor(bidx, s, 64);
                    bool take = (ov > bv) || (ov == bv && oi < bidx);
                    if (take) { bv = ov; bidx = oi; }
                }
                float wub = (float)__shfl(dvub, bidx, 64);
                if (lane == j) { out_logit = wub; out_idx = bidx; }
                if (lane == bidx) dcur = -(double)INFINITY;
            }
            float sv = (lane < TOPK) ? out_logit : -INFINITY;
            float mx = sv;
            mx = fmaxf(mx, __shfl_xor(mx, 1, 64));
            mx = fmaxf(mx, __shfl_xor(mx, 2, 64));
            mx = fmaxf(mx, __shfl_xor(mx, 4, 64));
            float e = (lane < TOPK) ? expf(sv - mx) : 0.f;
            float ssum = e;
            ssum += __shfl_xor(ssum, 1, 64);
            ssum += __shfl_xor(ssum, 2, 64);
            ssum += __shfl_xor(ssum, 4, 64);
            if (lane < TOPK) {
                float p = e / ssum;
                float r = rand_u[tt * TOPK + lane];
                out[tt * TOPK + lane] = (r > FILTER_R) ? p : 0.f;
                out[TOKENS * TOPK + tt * TOPK + lane] = (float)out_idx;
                atomicAdd(&hist_g[out_idx], 1);
            }
        }
        __syncthreads();
    }

    __threadfence();
    if (threadIdx.x == 0)
        last_flag = (atomicAdd(done_cnt, 1) == (int)gridDim.x - 1);
    __syncthreads();
    if (last_flag && threadIdx.x < NEXP) {
        int c = atomicAdd(&hist_g[threadIdx.x], 0);
        float e_i = (float)TOKENS / (float)NEXP - (float)c;
        float s = (e_i > 0.f) ? 1.f : ((e_i < 0.f) ? -1.f : 0.f);
        out[2 * TOKENS * TOPK + threadIdx.x] = bi[threadIdx.x] + LOAD_LR * s;
    }
}

extern "C" void kernel_launch(void* const* d_in, const int* in_sizes, int n_in,
                              void* d_out, int out_size, void* d_ws, size_t ws_size,
                              hipStream_t stream) {
    const float* x      = (const float*)d_in[0];
    const float* W      = (const float*)d_in[1];
    const float* b      = (const float*)d_in[2];
    const float* bi     = (const float*)d_in[3];
    const float* rand_u = (const float*)d_in[4];

    float* out = (float*)d_out;
    uint4* Bhi = (uint4*)d_ws;
    uint4* Blo = Bhi + BFRAG_U4;
    int*   hist = (int*)(Blo + BFRAG_U4);

    // 1) pack W -> bf16 hi/lo MFMA B-fragments; zero hist/flag/done
    pack_kernel<<<(NSTEP * 4 * 64) / 256, 256, 0, stream>>>(W, Bhi, Blo, hist);

    // 2) bf16x3 MFMA logits: coalesced x->LDS staging, disjoint per-wave outputs
    router_kernel<<<TOKENS / TPB, 256, 0, stream>>>(
        x, b, bi, rand_u, Bhi, Blo, out, hist);

    // 3) exact f64 redo for flagged tokens + fused bias update
    fallback_kernel<<<256, 256, 0, stream>>>(x, W, b, bi, rand_u, out, hist);
}

// Round 15
// 173.440 us; speedup vs baseline: 1.3461x; 1.3461x over previous
//
#include <hip/hip_runtime.h>
#include <hip/hip_bf16.h>
#include <math.h>

#define TOKENS 16384
#define DIM 4096
#define NEXP 64
#define TOPK 8
#define FILTER_R 0.62f
#define LOAD_LR 0.001f
#define EPS_GAP 1e-4f      // bf16x3 logit err ~1e-6 RMS; 100x margin

typedef __attribute__((ext_vector_type(8))) short bf16x8;
typedef __attribute__((ext_vector_type(4))) float f32x4;

#define NSTEP 128                  // total K-steps of 32
#define TPB 16                     // tokens per block
#define BK 256                     // floats per chunk per row (1KB rows)
#define NCH (DIM / BK)             // 16 chunks
#define BFRAG_U4 (NSTEP * 4 * 64)  // 32768 uint4 = 512KB per array

// ws: Bhi[512KB] | Blo[512KB] | hist[64] | flag_cnt | done_cnt | flag_list[16384]

__device__ __forceinline__ unsigned bf16_hi_bits(unsigned u) {
    return (u + 0x7fffu + ((u >> 16) & 1u)) & 0xffff0000u;   // RTNE bf16 (as f32 bits)
}

// Coalesced pack (R10-verified mapping): thread tid=((s*4+f)*64+lane) emits the
// 8 consecutive-k elems of one B-fragment slot: n=f*16+(lane&15), k=s*32+(lane>>4)*8+e
__global__ void pack_kernel(const float* __restrict__ W,
                            uint4* __restrict__ Bhi,
                            uint4* __restrict__ Blo,
                            int* __restrict__ hist) {
    int tid = blockIdx.x * blockDim.x + threadIdx.x;     // 0 .. 32767
    if (blockIdx.x == 0 && threadIdx.x < NEXP + 2) hist[threadIdx.x] = 0;
    int s = tid >> 8, f = (tid >> 6) & 3, lane = tid & 63;
    int n = f * 16 + (lane & 15);
    int k0 = s * 32 + ((lane >> 4) << 3);
    const float* wp = W + (size_t)n * DIM + k0;
    float4 wa = *(const float4*)wp;
    float4 wb = *(const float4*)(wp + 4);
    float fe[8] = {wa.x, wa.y, wa.z, wa.w, wb.x, wb.y, wb.z, wb.w};
    unsigned hh[8], ll[8];
#pragma unroll
    for (int e = 0; e < 8; ++e) {
        unsigned u = __float_as_uint(fe[e]);
        unsigned hr = bf16_hi_bits(u);
        hh[e] = hr >> 16;
        float lo = fe[e] - __uint_as_float(hr);
        ll[e] = bf16_hi_bits(__float_as_uint(lo)) >> 16;
    }
    Bhi[tid] = make_uint4(hh[0] | (hh[1] << 16), hh[2] | (hh[3] << 16),
                          hh[4] | (hh[5] << 16), hh[6] | (hh[7] << 16));
    Blo[tid] = make_uint4(ll[0] | (ll[1] << 16), ll[2] | (ll[3] << 16),
                          ll[4] | (ll[5] << 16), ll[6] | (ll[7] << 16));
}

#define MF(A, B, C) C = __builtin_amdgcn_mfma_f32_16x16x32_bf16(A, B, C, 0, 0, 0)

#define SPLIT8(A0, A1, AH, AL) {                                      \
    float fe[8] = {A0.x,A0.y,A0.z,A0.w,A1.x,A1.y,A1.z,A1.w};          \
    short he[8], le[8];                                               \
    _Pragma("unroll")                                                 \
    for (int e_ = 0; e_ < 8; ++e_) {                                  \
        unsigned u_ = __float_as_uint(fe[e_]);                        \
        unsigned hr_ = bf16_hi_bits(u_);                              \
        he[e_] = (short)(hr_ >> 16);                                  \
        float lo_ = fe[e_] - __uint_as_float(hr_);                    \
        le[e_] = (short)(bf16_hi_bits(__float_as_uint(lo_)) >> 16); } \
    AH = (bf16x8){he[0],he[1],he[2],he[3],he[4],he[5],he[6],he[7]};   \
    AL = (bf16x8){le[0],le[1],le[2],le[3],le[4],le[5],le[6],le[7]}; }

// 1024 blocks x 256 thr (4 waves = 4 F-quarters, full K each); 16 tokens/block.
// x staged via global_load_lds with ONE FULL 1KB ROW per instruction (sequential
// DRAM streams), XOR-unit pre-swizzle on source + same XOR on ds_read (rule #21).
// W direct from L2 (2 uint4/step/wave). 4 blocks/CU, 16 barriers total.
__global__ __launch_bounds__(256, 4) void router_kernel(
    const float* __restrict__ x,
    const float* __restrict__ b,
    const float* __restrict__ bi,
    const float* __restrict__ rand_u,
    const uint4* __restrict__ Bh4,
    const uint4* __restrict__ Bl4,
    float* __restrict__ out,          // probs | indices-as-float | bi_new
    int* __restrict__ hist_g) {       // hist[64] | flag_cnt | done_cnt | flag_list
    __shared__ float xs[2][TPB][BK];       // 32KB double-buffered x tile (swizzled)
    __shared__ float part[TPB][NEXP + 1];  // 4.2KB final logits (disjoint writes)
    __shared__ int lds_hist[NEXP];

    const int lane = threadIdx.x & 63;
    const int wid  = __builtin_amdgcn_readfirstlane(threadIdx.x >> 6);  // F-quarter
    if (threadIdx.x < NEXP) lds_hist[threadIdx.x] = 0;

    const int t0 = blockIdx.x * TPB;

    // stage chunk c into buffer bf: wave wid stages rows 4wid..4wid+3.
    // One instr = one complete row (64 lanes x 16B = 1KB contiguous global).
    // Source unit pre-swizzled (lane ^ (row&7)) so LDS slot i holds global
    // unit i^(row&7); reads use the same XOR -> bank-clean at the b128 floor.
    auto stage = [&](int c, int bf) {
#pragma unroll
        for (int i = 0; i < 4; ++i) {
            const int row = 4 * wid + i;
            const float* g = x + (size_t)(t0 + row) * DIM + c * BK
                               + ((lane ^ (row & 7)) << 2);
            __builtin_amdgcn_global_load_lds(
                (const __attribute__((address_space(1))) void*)g,
                (__attribute__((address_space(3))) void*)&xs[bf][row][0], 16, 0, 0);
        }
    };

    // 4 interleaved accumulator chains (static indices only - rule #20)
    f32x4 ac0 = {0,0,0,0}, ac1 = {0,0,0,0}, ac2 = {0,0,0,0}, ac3 = {0,0,0,0};
    const int r  = lane & 15;              // A row (token in tile)
    const int kg = lane >> 4;              // A k-subgroup (0..3)
    const int key = r & 7;                 // read-side XOR key

    stage(0, 0);
    __syncthreads();

    for (int c = 0; c < NCH; ++c) {
        const int bf = c & 1;
        if (c + 1 < NCH) stage(c + 1, bf ^ 1);

#pragma unroll
        for (int s = 0; s < 8; ++s) {          // 8 K-steps of 32 per chunk
            const int u0 = s * 8 + ((2 * kg) ^ key);
            const int u1 = s * 8 + ((2 * kg + 1) ^ key);
            float4 xa = *(const float4*)&xs[bf][r][u0 << 2];
            float4 xb = *(const float4*)&xs[bf][r][u1 << 2];
            bf16x8 ah, al;
            SPLIT8(xa, xb, ah, al);
            const size_t S = (size_t)c * 8 + s;            // global K-step
            uint4 bhv = Bh4[(S * 4 + wid) * 64 + lane];
            uint4 blv = Bl4[(S * 4 + wid) * 64 + lane];
            bf16x8 bh_ = __builtin_bit_cast(bf16x8, bhv);
            bf16x8 bl_ = __builtin_bit_cast(bf16x8, blv);
            if ((s & 3) == 0) { MF(ah, bh_, ac0); MF(al, bh_, ac0); MF(ah, bl_, ac0); }
            if ((s & 3) == 1) { MF(ah, bh_, ac1); MF(al, bh_, ac1); MF(ah, bl_, ac1); }
            if ((s & 3) == 2) { MF(ah, bh_, ac2); MF(al, bh_, ac2); MF(ah, bl_, ac2); }
            if ((s & 3) == 3) { MF(ah, bh_, ac3); MF(al, bh_, ac3); MF(ah, bl_, ac3); }
        }
        __syncthreads();
    }

    f32x4 acc;
#pragma unroll
    for (int e = 0; e < 4; ++e) acc[e] = (ac0[e] + ac1[e]) + (ac2[e] + ac3[e]);

    // disjoint C write: token = kg*4 + rr, expert = wid*16 + (lane&15)
#pragma unroll
    for (int rr = 0; rr < 4; ++rr)
        part[kg * 4 + rr][wid * 16 + r] = acc[rr];
    __syncthreads();

    const float b_lane  = b[lane];
    const float bi_lane = bi[lane];
    int* flag_cnt  = hist_g + NEXP;
    int* flag_list = hist_g + NEXP + 2;

    for (int t = wid * 4; t < wid * 4 + 4; ++t) {
        const float vub = part[t][lane] + b_lane;
        float cur_l = vub + bi_lane;

        float selv  = -INFINITY;
        int   selidx = 0;
#pragma unroll
        for (int j = 0; j <= TOPK; ++j) {       // top-9: gap-check 8/9 boundary too
            float bv = cur_l;
            int   bidx = lane;
#pragma unroll
            for (int s = 1; s < 64; s <<= 1) {
                float ov = __shfl_xor(bv, s, 64);
                int   oi = __shfl_xor(bidx, s, 64);
                bool take = (ov > bv) || (ov == bv && oi < bidx);
                if (take) { bv = ov; bidx = oi; }
            }
            if (lane == j) { selv = bv; selidx = bidx; }
            if (lane == bidx) cur_l = -INFINITY;
        }

        const int tt = t0 + t;
        float nxtv = __shfl_down(selv, 1, 64);
        bool  bad  = (lane < TOPK) && (selv - nxtv < EPS_GAP);
        if (__any(bad)) {
            if (lane == 0) {
                int p = atomicAdd(flag_cnt, 1);
                if (p < TOKENS) flag_list[p] = tt;
            }
        } else {
            float out_logit = __shfl(vub, selidx, 64);
            float sv = (lane < TOPK) ? out_logit : -INFINITY;
            float mx = sv;
            mx = fmaxf(mx, __shfl_xor(mx, 1, 64));
            mx = fmaxf(mx, __shfl_xor(mx, 2, 64));
            mx = fmaxf(mx, __shfl_xor(mx, 4, 64));
            float e = (lane < TOPK) ? expf(sv - mx) : 0.f;
            float ssum = e;
            ssum += __shfl_xor(ssum, 1, 64);
            ssum += __shfl_xor(ssum, 2, 64);
            ssum += __shfl_xor(ssum, 4, 64);
            if (lane < TOPK) {
                float p = e / ssum;
                float rr = rand_u[tt * TOPK + lane];
                out[tt * TOPK + lane] = (rr > FILTER_R) ? p : 0.f;
                out[TOKENS * TOPK + tt * TOPK + lane] = (float)selidx;
                atomicAdd(&lds_hist[selidx], 1);
            }
        }
    }

    __syncthreads();
    if (threadIdx.x < NEXP) atomicAdd(&hist_g[threadIdx.x], lds_hist[threadIdx.x]);
}

// exact f64 redo per flagged token (4-wave K-split); last block does bias update
__global__ __launch_bounds__(256) void fallback_kernel(
    const float* __restrict__ x,
    const float* __restrict__ W,
    const float* __restrict__ b,
    const float* __restrict__ bi,
    const float* __restrict__ rand_u,
    float* __restrict__ out,
    int* __restrict__ hist_g) {
    __shared__ double part[4][64];
    __shared__ int last_flag;
    const int lane = threadIdx.x & 63;
    const int wave = threadIdx.x >> 6;
    const int* flag_cnt  = hist_g + NEXP;
    int* done_cnt        = hist_g + NEXP + 1;
    const int* flag_list = hist_g + NEXP + 2;
    int n = *flag_cnt; if (n > TOKENS) n = TOKENS;

    for (int i = blockIdx.x; i < n; i += gridDim.x) {
        const int tt = flag_list[i];
        const float4* xr = (const float4*)(x + (size_t)tt * DIM);
        const float4* wr = (const float4*)(W + (size_t)lane * DIM);
        double d0 = 0.0, d1 = 0.0;
#pragma unroll 8
        for (int k4 = wave * 256; k4 < (wave + 1) * 256; ++k4) {
            float4 xv = xr[k4];
            float4 wv = wr[k4];
            d0 = fma((double)xv.x, (double)wv.x, d0);
            d1 = fma((double)xv.y, (double)wv.y, d1);
            d0 = fma((double)xv.z, (double)wv.z, d0);
            d1 = fma((double)xv.w, (double)wv.w, d1);
        }
        part[wave][lane] = d0 + d1;
        __syncthreads();
        if (wave == 0) {
            const double dvub = ((part[0][lane] + part[1][lane]) +
                                 (part[2][lane] + part[3][lane])) + (double)b[lane];
            double dcur = dvub + (double)bi[lane];
            float out_logit = -INFINITY;
            int   out_idx   = 0;
#pragma unroll
            for (int j = 0; j < TOPK; ++j) {
                double bv = dcur;
                int    bidx = lane;
#pragma unroll
                for (int s = 1; s < 64; s <<= 1) {
                    double ov = __shfl_xor(bv, s, 64);
                    int    oi = __shfl_xor(bidx, s, 64);
                    bool take = (ov > bv) || (ov == bv && oi < bidx);
                    if (take) { bv = ov; bidx = oi; }
                }
                float wub = (float)__shfl(dvub, bidx, 64);
                if (lane == j) { out_logit = wub; out_idx = bidx; }
                if (lane == bidx) dcur = -(double)INFINITY;
            }
            float sv = (lane < TOPK) ? out_logit : -INFINITY;
            float mx = sv;
            mx = fmaxf(mx, __shfl_xor(mx, 1, 64));
            mx = fmaxf(mx, __shfl_xor(mx, 2, 64));
            mx = fmaxf(mx, __shfl_xor(mx, 4, 64));
            float e = (lane < TOPK) ? expf(sv - mx) : 0.f;
            float ssum = e;
            ssum += __shfl_xor(ssum, 1, 64);
            ssum += __shfl_xor(ssum, 2, 64);
            ssum += __shfl_xor(ssum, 4, 64);
            if (lane < TOPK) {
                float p = e / ssum;
                float r = rand_u[tt * TOPK + lane];
                out[tt * TOPK + lane] = (r > FILTER_R) ? p : 0.f;
                out[TOKENS * TOPK + tt * TOPK + lane] = (float)out_idx;
                atomicAdd(&hist_g[out_idx], 1);
            }
        }
        __syncthreads();
    }

    __threadfence();
    if (threadIdx.x == 0)
        last_flag = (atomicAdd(done_cnt, 1) == (int)gridDim.x - 1);
    __syncthreads();
    if (last_flag && threadIdx.x < NEXP) {
        int c = atomicAdd(&hist_g[threadIdx.x], 0);
        float e_i = (float)TOKENS / (float)NEXP - (float)c;
        float s = (e_i > 0.f) ? 1.f : ((e_i < 0.f) ? -1.f : 0.f);
        out[2 * TOKENS * TOPK + threadIdx.x] = bi[threadIdx.x] + LOAD_LR * s;
    }
}

extern "C" void kernel_launch(void* const* d_in, const int* in_sizes, int n_in,
                              void* d_out, int out_size, void* d_ws, size_t ws_size,
                              hipStream_t stream) {
    const float* x      = (const float*)d_in[0];
    const float* W      = (const float*)d_in[1];
    const float* b      = (const float*)d_in[2];
    const float* bi     = (const float*)d_in[3];
    const float* rand_u = (const float*)d_in[4];

    float* out = (float*)d_out;
    uint4* Bhi = (uint4*)d_ws;
    uint4* Blo = Bhi + BFRAG_U4;
    int*   hist = (int*)(Blo + BFRAG_U4);

    // 1) pack W -> bf16 hi/lo MFMA B-fragments; zero hist/flag/done
    pack_kernel<<<(NSTEP * 4 * 64) / 256, 256, 0, stream>>>(W, Bhi, Blo, hist);

    // 2) bf16x3 MFMA logits: row-contiguous x staging, 4 blocks/CU, 16 barriers
    router_kernel<<<TOKENS / TPB, 256, 0, stream>>>(
        x, b, bi, rand_u, Bhi, Blo, out, hist);

    // 3) exact f64 redo for flagged tokens + fused bias update
    fallback_kernel<<<256, 256, 0, stream>>>(x, W, b, bi, rand_u, out, hist);
}